// Round 7
// baseline (568.063 us; speedup 1.0000x reference)
//
#include <hip/hip_runtime.h>

// 3D Jacobi (6-neighbor), 20 sweeps, zero-Dirichlet.
// step_first_v (padded pre -> out + g=h^2*f) + 9x fused double-sweeps
// (register-ring 2.5D pipeline: u-ring + w-ring in VGPRs, x-neighbors via
// shuffles, 2 LDS reads/phase, 1 barrier/iter) + 1 single float4 sweep.

#define NP 258
#define NI 256
#define HHC ((1.0f / 257.0f) * (1.0f / 257.0f))
#define SIXTH (1.0f / 6.0f)

#define TX 32
#define TY 32
#define CZ 16

__device__ __forceinline__ float4 ld4u(const float* p) {
    float4 v; __builtin_memcpy(&v, p, sizeof(float4)); return v;
}
__device__ __forceinline__ float4 zero4() { return make_float4(0.f, 0.f, 0.f, 0.f); }
__device__ __forceinline__ float4 ldg4(const float* p) {
    return *reinterpret_cast<const float4*>(p);
}

// First sweep, vectorized: padded pre (incl. random halo) -> out, g = h^2*f.
__global__ void step_first_v(const float* __restrict__ pre,
                             const float* __restrict__ f,
                             float* __restrict__ out,
                             float* __restrict__ g) {
    const int tx = threadIdx.x;
    const int y  = blockIdx.y * 4 + threadIdx.y;
    const int z  = blockIdx.z;
    const int gx0 = 4 * tx;
    const size_t sP = (size_t)NP * NP;
    const size_t prow = (size_t)(z + 1) * sP + (size_t)(y + 1) * NP + 1;

    const float4 C  = ld4u(&pre[prow + gx0]);
    const float4 up = ld4u(&pre[prow - NP + gx0]);
    const float4 dn = ld4u(&pre[prow + NP + gx0]);
    const float4 zm = ld4u(&pre[prow - sP + gx0]);
    const float4 zp = ld4u(&pre[prow + sP + gx0]);
    float4 fv = ld4u(&f[prow + gx0]);
    fv.x *= HHC; fv.y *= HHC; fv.z *= HHC; fv.w *= HHC;

    float lft = __shfl_up(C.w, 1);
    if (tx == 0)  lft = pre[prow + gx0 - 1];
    float rgt = __shfl_down(C.x, 1);
    if (tx == 63) rgt = pre[prow + gx0 + 4];

    float4 o;
    o.x = (lft + C.y + up.x + dn.x + zm.x + zp.x + fv.x) * SIXTH;
    o.y = (C.x + C.z + up.y + dn.y + zm.y + zp.y + fv.y) * SIXTH;
    o.z = (C.y + C.w + up.z + dn.z + zm.z + zp.z + fv.z) * SIXTH;
    o.w = (C.z + rgt + up.w + dn.w + zm.w + zp.w + fv.w) * SIXTH;

    const size_t oi = ((size_t)z * NI + y) * NI + gx0;
    *reinterpret_cast<float4*>(&out[oi]) = o;
    *reinterpret_cast<float4*>(&g[oi])  = fv;
}

// Final single sweep, float4, using g.
__global__ void step_last_v(const float4* __restrict__ u4,
                            const float4* __restrict__ g4,
                            float4* __restrict__ out4) {
    const int tx = threadIdx.x;
    const int y  = blockIdx.y * 4 + threadIdx.y;
    const int z  = blockIdx.z;
    const int rowq   = NI / 4;
    const int planeq = NI * rowq;
    const int r = z * planeq + y * rowq + tx;

    const float4 v = u4[r];
    float left  = __shfl_up(v.w, 1);
    float right = __shfl_down(v.x, 1);
    if (tx == 0)  left  = 0.0f;
    if (tx == 63) right = 0.0f;

    float4 nb;
    nb.x = left + v.y;
    nb.y = v.x  + v.z;
    nb.z = v.y  + v.w;
    nb.w = v.z  + right;

    if (y > 0)      { float4 b = u4[r - rowq];   nb.x += b.x; nb.y += b.y; nb.z += b.z; nb.w += b.w; }
    if (y < NI - 1) { float4 b = u4[r + rowq];   nb.x += b.x; nb.y += b.y; nb.z += b.z; nb.w += b.w; }
    if (z > 0)      { float4 b = u4[r - planeq]; nb.x += b.x; nb.y += b.y; nb.z += b.z; nb.w += b.w; }
    if (z < NI - 1) { float4 b = u4[r + planeq]; nb.x += b.x; nb.y += b.y; nb.z += b.z; nb.w += b.w; }

    const float4 gv = g4[r];
    float4 o;
    o.x = (nb.x + gv.x) * SIXTH;
    o.y = (nb.y + gv.y) * SIXTH;
    o.z = (nb.z + gv.z) * SIXTH;
    o.w = (nb.w + gv.w) * SIXTH;
    out4[r] = o;
}

// Fused double sweep out = J(J(u)), register-ring pipeline.
// Roles per thread (fixed):
//  A (tid<432): stage u plane t+2 into su (prefetched reg ru).
//  W (tid<340): compute w(t+1) using u-ring (regs) + shuffles + 2 su reads; write sw.
//  O (interior W): out(t) using w-ring (regs) + shuffles + 2 sw reads.
// One barrier per z-iter (all intra-iter slot accesses disjoint by parity).
__global__ __launch_bounds__(512, 4)
void step_fused2r(const float* __restrict__ u,
                  const float* __restrict__ g,
                  float* __restrict__ out) {
    __shared__ float4 su[2][36][13];   // u planes: x [x0-8,x0+40) 12 chunks (+pad), y [y0-2,y0+34)
    __shared__ float4 sw[2][34][11];   // w planes: x [x0-4,x0+36) 10 chunks (+pad), y [y0-1,y0+33)

    const int tid = threadIdx.x;

    // XCD-contiguous tile remap (grid 8x8x16 = 1024 = 8 XCDs x 128).
    const int lid = blockIdx.x + (blockIdx.y << 3) + (blockIdx.z << 6);
    const int swzid = (lid & 7) * 128 + (lid >> 3);
    const int x0 = (swzid & 7) * TX;
    const int y0 = ((swzid >> 3) & 7) * TY;
    const int z0 = (swzid >> 6) * CZ;
    const int zend = z0 + CZ;
    const int plq = NI * NI;

    // A mapping: 432 threads, one f4 chunk of su.
    const int lr = tid / 12, lc = tid - lr * 12;
    const bool lact = tid < 432;
    const int lgy = y0 - 2 + lr, lgx0 = x0 - 8 + 4 * lc;
    const bool lxy = lact && lgy >= 0 && lgy < NI && lgx0 >= 0 && lgx0 < NI;
    const int lbase = lgy * NI + lgx0;

    // W mapping: 340 threads, one w f4.
    const int wr = tid / 10, wc = tid - wr * 10;
    const bool wact = tid < 340;
    const int wgy = y0 - 1 + wr, wgx0 = x0 - 4 + 4 * wc;
    const bool wxy = wact && wgy >= 0 && wgy < NI && wgx0 >= 0 && wgx0 < NI;
    const int wbase = wgy * NI + wgx0;

    // O: interior W threads.
    const bool oact = wact && wr >= 1 && wr <= 32 && wc >= 1 && wc <= 8;
    const int obase = (y0 + wr - 1) * NI + (x0 + 4 * (wc - 1));

    // Registers: rings + prefetch.
    float4 u_c = zero4(), u_zp = zero4(), ucn = zero4(), ru = zero4();
    float4 w_zm = zero4(), w_c = zero4(), w_zp = zero4();
    float4 gwn = zero4();

    // Prologue: ru <- u plane z0-1 (A writes it at t = z0-3);
    // u-ring seeds: u_zp <- u(z0-2), ucn <- u(z0-1).
    {
        const int pl = z0 - 1;
        if (lxy && pl >= 0) ru = ldg4(&u[(size_t)pl * plq + lbase]);
        if (wxy) {
            if (z0 - 2 >= 0) u_zp = ldg4(&u[(size_t)(z0 - 2) * plq + wbase]);
            if (z0 - 1 >= 0) ucn  = ldg4(&u[(size_t)(z0 - 1) * plq + wbase]);
        }
    }

    for (int t = z0 - 3; t < zend; ++t) {
        // ---- A: stage su plane t+2 (slot (t+2)&1); issue load of plane t+3 ----
        if (lact) su[(t + 2) & 1][lr][lc] = ru;
        ru = zero4();
        {
            const int pl = t + 3;
            if (t < zend - 1 && pl < NI && lxy)
                ru = ldg4(&u[(size_t)pl * plq + lbase]);
        }
        // ---- u-ring push; issue own-column load of plane t+3 ----
        const float4 u_zm = u_c;
        u_c = u_zp; u_zp = ucn;
        ucn = zero4();
        {
            const int pl = t + 3;
            if (t < zend - 1 && pl < NI && wxy)
                ucn = ldg4(&u[(size_t)pl * plq + wbase]);
        }
        const float4 gw = gwn;
        gwn = zero4();
        {
            const int p2 = t + 2;
            if (t < zend - 1 && p2 >= 0 && p2 < NI && wxy)
                gwn = ldg4(&g[(size_t)p2 * plq + wbase]);
        }

        // ---- W: compute w(t+1) ----
        // shuffles run for all lanes (sources must be live)
        const float scpw = __shfl_up(u_c.w, 1);
        const float scnx = __shfl_down(u_c.x, 1);
        float4 wv = zero4();
        const int pw = t + 1;
        if (wact && t >= z0 - 2 && wxy && pw >= 0 && pw < NI) {
            const int s = pw & 1;
            const float4 uy = su[s][wr][wc + 1];
            const float4 dy = su[s][wr + 2][wc + 1];
            float lft = scpw, rgt = scnx;
            if (wc == 0 || (tid & 63) == 0)  lft = su[s][wr + 1][wc].w;
            if (wc == 9 || (tid & 63) == 63) rgt = su[s][wr + 1][wc + 2].x;
            wv.x = (lft   + u_c.y + uy.x + dy.x + u_zm.x + u_zp.x + gw.x) * SIXTH;
            wv.y = (u_c.x + u_c.z + uy.y + dy.y + u_zm.y + u_zp.y + gw.y) * SIXTH;
            wv.z = (u_c.y + u_c.w + uy.z + dy.z + u_zm.z + u_zp.z + gw.z) * SIXTH;
            wv.w = (u_c.z + rgt   + uy.w + dy.w + u_zm.w + u_zp.w + gw.w) * SIXTH;
        }
        // w-ring push + sw write
        w_zm = w_c; w_c = w_zp; w_zp = wv;
        if (wact) sw[pw & 1][wr][wc] = wv;

        // ---- O: out plane t (uses w-ring; sw plane t written last iter) ----
        const float ocpw = __shfl_up(w_c.w, 1);
        const float ocnx = __shfl_down(w_c.x, 1);
        if (oact && t >= z0) {
            const int s = t & 1;
            const float4 uy = sw[s][wr - 1][wc];
            const float4 dy = sw[s][wr + 1][wc];
            float lft = ocpw, rgt = ocnx;
            if ((tid & 63) == 0)  lft = sw[s][wr][wc - 1].w;
            if ((tid & 63) == 63) rgt = sw[s][wr][wc + 1].x;
            const float4 go = ldg4(&g[(size_t)t * plq + obase]);
            float4 ov;
            ov.x = (lft   + w_c.y + uy.x + dy.x + w_zm.x + w_zp.x + go.x) * SIXTH;
            ov.y = (w_c.x + w_c.z + uy.y + dy.y + w_zm.y + w_zp.y + go.y) * SIXTH;
            ov.z = (w_c.y + w_c.w + uy.z + dy.z + w_zm.z + w_zp.z + go.z) * SIXTH;
            ov.w = (w_c.z + rgt   + uy.w + dy.w + w_zm.w + w_zp.w + go.w) * SIXTH;
            *reinterpret_cast<float4*>(&out[(size_t)t * plq + obase]) = ov;
        }
        __syncthreads();
    }
}

extern "C" void kernel_launch(void* const* d_in, const int* in_sizes, int n_in,
                              void* d_out, int out_size, void* d_ws, size_t ws_size,
                              hipStream_t stream) {
    const float* pre = (const float*)d_in[0];
    const float* f   = (const float*)d_in[1];
    float* out = (float*)d_out;
    float* buf = (float*)d_ws;
    const size_t nInt = (size_t)NI * NI * NI;
    float* g = buf + nInt;                              // g = h^2*f (ws >= 128 MiB)

    // 20 sweeps: step_first (1) + 9 fused (18) + 1 single.
    step_first_v<<<dim3(1, NI / 4, NI), dim3(64, 4, 1), 0, stream>>>(pre, f, out, g);

    float* cur = out;
    float* nxt = buf;
    dim3 fg(NI / TX, NI / TY, NI / CZ);                 // 8x8x16 = 1024 blocks
    for (int i = 0; i < 9; ++i) {
        step_fused2r<<<fg, dim3(512, 1, 1), 0, stream>>>(cur, g, nxt);
        float* tmp = cur; cur = nxt; nxt = tmp;
    }
    // cur == buf after 9 swaps; final single sweep buf -> out.
    step_last_v<<<dim3(1, NI / 4, NI), dim3(64, 4, 1), 0, stream>>>(
        (const float4*)cur, (const float4*)g, (float4*)out);
}

// Round 9
// 477.144 us; speedup vs baseline: 1.1905x; 1.1905x over previous
//
#include <hip/hip_runtime.h>

// 3D Jacobi (6-neighbor), 20 sweeps, zero-Dirichlet.
// step_first_v (padded pre -> out + g=h^2*f) + 9x fused double-sweeps
// (2.5D z-march; u/w/g column rings in registers, LDS only for xy-neighbor
// exchange, all LDS accesses tid-contiguous) + 1 single float4 sweep.

#define NP 258
#define NI 256
#define HHC ((1.0f / 257.0f) * (1.0f / 257.0f))
#define SIXTH (1.0f / 6.0f)

#define TX 32
#define TY 32
#define CZ 16

__device__ __forceinline__ float4 ld4u(const float* p) {
    float4 v; __builtin_memcpy(&v, p, sizeof(float4)); return v;
}
__device__ __forceinline__ float4 zero4() { return make_float4(0.f, 0.f, 0.f, 0.f); }
__device__ __forceinline__ float4 ldg4(const float* p) {
    return *reinterpret_cast<const float4*>(p);
}

// First sweep, vectorized: padded pre (incl. random halo) -> out, g = h^2*f.
__global__ void step_first_v(const float* __restrict__ pre,
                             const float* __restrict__ f,
                             float* __restrict__ out,
                             float* __restrict__ g) {
    const int tx = threadIdx.x;
    const int y  = blockIdx.y * 4 + threadIdx.y;
    const int z  = blockIdx.z;
    const int gx0 = 4 * tx;
    const size_t sP = (size_t)NP * NP;
    const size_t prow = (size_t)(z + 1) * sP + (size_t)(y + 1) * NP + 1;

    const float4 C  = ld4u(&pre[prow + gx0]);
    const float4 up = ld4u(&pre[prow - NP + gx0]);
    const float4 dn = ld4u(&pre[prow + NP + gx0]);
    const float4 zm = ld4u(&pre[prow - sP + gx0]);
    const float4 zp = ld4u(&pre[prow + sP + gx0]);
    float4 fv = ld4u(&f[prow + gx0]);
    fv.x *= HHC; fv.y *= HHC; fv.z *= HHC; fv.w *= HHC;

    float lft = __shfl_up(C.w, 1);
    if (tx == 0)  lft = pre[prow + gx0 - 1];
    float rgt = __shfl_down(C.x, 1);
    if (tx == 63) rgt = pre[prow + gx0 + 4];

    float4 o;
    o.x = (lft + C.y + up.x + dn.x + zm.x + zp.x + fv.x) * SIXTH;
    o.y = (C.x + C.z + up.y + dn.y + zm.y + zp.y + fv.y) * SIXTH;
    o.z = (C.y + C.w + up.z + dn.z + zm.z + zp.z + fv.z) * SIXTH;
    o.w = (C.z + rgt + up.w + dn.w + zm.w + zp.w + fv.w) * SIXTH;

    const size_t oi = ((size_t)z * NI + y) * NI + gx0;
    *reinterpret_cast<float4*>(&out[oi]) = o;
    *reinterpret_cast<float4*>(&g[oi])  = fv;
}

// Final single sweep, float4, using g.
__global__ void step_last_v(const float4* __restrict__ u4,
                            const float4* __restrict__ g4,
                            float4* __restrict__ out4) {
    const int tx = threadIdx.x;
    const int y  = blockIdx.y * 4 + threadIdx.y;
    const int z  = blockIdx.z;
    const int rowq   = NI / 4;
    const int planeq = NI * rowq;
    const int r = z * planeq + y * rowq + tx;

    const float4 v = u4[r];
    float left  = __shfl_up(v.w, 1);
    float right = __shfl_down(v.x, 1);
    if (tx == 0)  left  = 0.0f;
    if (tx == 63) right = 0.0f;

    float4 nb;
    nb.x = left + v.y;
    nb.y = v.x  + v.z;
    nb.z = v.y  + v.w;
    nb.w = v.z  + right;

    if (y > 0)      { float4 b = u4[r - rowq];   nb.x += b.x; nb.y += b.y; nb.z += b.z; nb.w += b.w; }
    if (y < NI - 1) { float4 b = u4[r + rowq];   nb.x += b.x; nb.y += b.y; nb.z += b.z; nb.w += b.w; }
    if (z > 0)      { float4 b = u4[r - planeq]; nb.x += b.x; nb.y += b.y; nb.z += b.z; nb.w += b.w; }
    if (z < NI - 1) { float4 b = u4[r + planeq]; nb.x += b.x; nb.y += b.y; nb.z += b.z; nb.w += b.w; }

    const float4 gv = g4[r];
    float4 o;
    o.x = (nb.x + gv.x) * SIXTH;
    o.y = (nb.y + gv.y) * SIXTH;
    o.z = (nb.z + gv.z) * SIXTH;
    o.w = (nb.w + gv.w) * SIXTH;
    out4[r] = o;
}

// Fused double sweep out = J(J(u)).
// Roles per thread (r10 = tid/10, c10 = tid%10):
//  A (tid<360): stage u plane t+2 -> su[t&1] (prefetched reg), addr = tid (contiguous).
//  W (tid<340): w(t+1) from u-ring (cc,zm,zp regs) + su reads {uy,dy,cp,cn,zp}; write sw.
//  O (interior W): out(t) from w-ring (cc,zm,zp regs) + sw reads {uy,dy,cp,cn} + g-ring.
// su/sw ring-2 by plane parity; 2 barriers/iter.
__global__ __launch_bounds__(384, 6)
void step_fused2q(const float* __restrict__ u,
                  const float* __restrict__ g,
                  float* __restrict__ out) {
    __shared__ float4 su[2][36][10];   // u planes: y [y0-2,y0+34), x [x0-4,x0+36)
    __shared__ float4 sw[2][34][10];   // w planes: y [y0-1,y0+33), x [x0-4,x0+36)

    const int tid = threadIdx.x;

    // XCD-contiguous tile remap (grid 8x8x16 = 1024 = 8 XCDs x 128).
    const int lid = blockIdx.x + (blockIdx.y << 3) + (blockIdx.z << 6);
    const int swzid = (lid & 7) * 128 + (lid >> 3);
    const int x0 = (swzid & 7) * TX;
    const int y0 = ((swzid >> 3) & 7) * TY;
    const int z0 = (swzid >> 6) * CZ;
    const int zend = z0 + CZ;
    const int plq = NI * NI;

    const int r10 = tid / 10, c10 = tid - r10 * 10;

    // A mapping (360 threads)
    const bool lact = tid < 360;
    const int lgy = y0 - 2 + r10;
    const int gx0c = x0 - 4 + 4 * c10;          // shared x formula for A and W
    const bool lxy = lact && lgy >= 0 && lgy < NI && gx0c >= 0 && gx0c < NI;
    const int lbase = lgy * NI + gx0c;

    // W mapping (340 threads)
    const bool wact = tid < 340;
    const int wgy = y0 - 1 + r10;
    const bool wxy = wact && wgy >= 0 && wgy < NI && gx0c >= 0 && gx0c < NI;
    const int wbase = wgy * NI + gx0c;
    const int wcm = (c10 > 0) ? c10 - 1 : 0;    // clamped; garbage confined to unused comps
    const int wcp = (c10 < 9) ? c10 + 1 : 9;

    // O: interior W threads (out position == w position)
    const bool oact = wact && r10 >= 1 && r10 <= 32 && c10 >= 1 && c10 <= 8;

    // Register rings + prefetch
    float4 ru = zero4();                                   // A staging
    float4 u_zm = zero4(), u_c = zero4(), u_zp = zero4();  // u column (W)
    float4 w_zm = zero4(), w_c = zero4(), w_zp = zero4();  // w column (O)
    float4 g0 = zero4(), g1 = zero4(), gn = zero4();       // g(t), g(t+1), g(t+2)

    {   // prologue: ru <- u plane z0-2 (stored at first A)
        const int pl = z0 - 2;
        if (lxy && pl >= 0) ru = ldg4(&u[(size_t)pl * plq + lbase]);
    }

    for (int t = z0 - 4; t < zend; ++t) {
        // ---- A: store su plane t+2 (slot t&1); prefetch plane t+3; g prefetch t+2 ----
        if (lact) su[t & 1][r10][c10] = ru;
        ru = zero4();
        {
            const int pl = t + 3;
            if (t < zend - 1 && pl >= 0 && pl < NI && lxy)
                ru = ldg4(&u[(size_t)pl * plq + lbase]);
        }
        gn = zero4();
        {
            const int p = t + 2;
            if (t < zend - 1 && p >= 0 && p < NI && wxy)
                gn = ldg4(&g[(size_t)p * plq + wbase]);
        }
        __syncthreads();

        // ---- W: u-ring shift + zp read; compute w(t+1); write sw; w-ring shift ----
        float4 wv = zero4();
        if (wact) {
            u_zm = u_c; u_c = u_zp;
            u_zp = su[t & 1][r10 + 1][c10];                // plane t+2, addr tid+10
            const int pw = t + 1;
            if (t >= z0 - 2 && wxy && pw >= 0 && pw < NI) {   // FIX: pw >= 0 guard
                const int s1 = (t + 1) & 1;
                const float4 uy = su[s1][r10][c10];        // addr tid
                const float4 dy = su[s1][r10 + 2][c10];    // addr tid+20
                const float4 cp = su[s1][r10 + 1][wcm];    // addr tid+9/10
                const float4 cn = su[s1][r10 + 1][wcp];    // addr tid+11/10
                wv.x = (cp.w  + u_c.y + uy.x + dy.x + u_zm.x + u_zp.x + g1.x) * SIXTH;
                wv.y = (u_c.x + u_c.z + uy.y + dy.y + u_zm.y + u_zp.y + g1.y) * SIXTH;
                wv.z = (u_c.y + u_c.w + uy.z + dy.z + u_zm.z + u_zp.z + g1.z) * SIXTH;
                wv.w = (u_c.z + cn.x  + uy.w + dy.w + u_zm.w + u_zp.w + g1.w) * SIXTH;
            }
            sw[(t + 1) & 1][r10][c10] = wv;
            w_zm = w_c; w_c = w_zp; w_zp = wv;             // now: w_c = w(t), w_zp = w(t+1)
        }
        __syncthreads();

        // ---- O: out plane t from w-ring + sw plane t ----
        if (oact && t >= z0) {
            const int s0 = t & 1;
            const float4 uy = sw[s0][r10 - 1][c10];        // addr tid-10
            const float4 dy = sw[s0][r10 + 1][c10];        // addr tid+10
            const float4 cp = sw[s0][r10][c10 - 1];        // addr tid-1
            const float4 cn = sw[s0][r10][c10 + 1];        // addr tid+1
            float4 ov;
            ov.x = (cp.w  + w_c.y + uy.x + dy.x + w_zm.x + w_zp.x + g0.x) * SIXTH;
            ov.y = (w_c.x + w_c.z + uy.y + dy.y + w_zm.y + w_zp.y + g0.y) * SIXTH;
            ov.z = (w_c.y + w_c.w + uy.z + dy.z + w_zm.z + w_zp.z + g0.z) * SIXTH;
            ov.w = (w_c.z + cn.x  + uy.w + dy.w + w_zm.w + w_zp.w + g0.w) * SIXTH;
            *reinterpret_cast<float4*>(&out[(size_t)t * plq + wbase]) = ov;
        }
        // g-ring shift (end of iter): g0 <- g(t+1), g1 <- g(t+2)
        g0 = g1; g1 = gn;
    }
}

extern "C" void kernel_launch(void* const* d_in, const int* in_sizes, int n_in,
                              void* d_out, int out_size, void* d_ws, size_t ws_size,
                              hipStream_t stream) {
    const float* pre = (const float*)d_in[0];
    const float* f   = (const float*)d_in[1];
    float* out = (float*)d_out;
    float* buf = (float*)d_ws;
    const size_t nInt = (size_t)NI * NI * NI;
    float* g = buf + nInt;                              // g = h^2*f (ws >= 128 MiB)

    // 20 sweeps: step_first (1) + 9 fused (18) + 1 single.
    step_first_v<<<dim3(1, NI / 4, NI), dim3(64, 4, 1), 0, stream>>>(pre, f, out, g);

    float* cur = out;
    float* nxt = buf;
    dim3 fg(NI / TX, NI / TY, NI / CZ);                 // 8x8x16 = 1024 blocks
    for (int i = 0; i < 9; ++i) {
        step_fused2q<<<fg, dim3(384, 1, 1), 0, stream>>>(cur, g, nxt);
        float* tmp = cur; cur = nxt; nxt = tmp;
    }
    // cur == buf after 9 swaps; final single sweep buf -> out.
    step_last_v<<<dim3(1, NI / 4, NI), dim3(64, 4, 1), 0, stream>>>(
        (const float4*)cur, (const float4*)g, (float4*)out);
}

// Round 10
// 465.023 us; speedup vs baseline: 1.2216x; 1.0261x over previous
//
#include <hip/hip_runtime.h>

// 3D Jacobi (6-neighbor), 20 sweeps, zero-Dirichlet.
// step_first_v (padded pre -> out + g=h^2*f) + 9x fused double-sweeps
// (unified-position 2.5D pipeline, y-pair batching, register z-rings,
// 1 barrier/iter) + 1 single float4 sweep.

#define NP 258
#define NI 256
#define HHC ((1.0f / 257.0f) * (1.0f / 257.0f))
#define SIXTH (1.0f / 6.0f)

#define TX 32
#define TY 32
#define CZ 16

__device__ __forceinline__ float4 ld4u(const float* p) {
    float4 v; __builtin_memcpy(&v, p, sizeof(float4)); return v;
}
__device__ __forceinline__ float4 zero4() { return make_float4(0.f, 0.f, 0.f, 0.f); }
__device__ __forceinline__ float4 ldg4(const float* p) {
    return *reinterpret_cast<const float4*>(p);
}

// First sweep, vectorized: padded pre (incl. random halo) -> out, g = h^2*f.
__global__ void step_first_v(const float* __restrict__ pre,
                             const float* __restrict__ f,
                             float* __restrict__ out,
                             float* __restrict__ g) {
    const int tx = threadIdx.x;
    const int y  = blockIdx.y * 4 + threadIdx.y;
    const int z  = blockIdx.z;
    const int gx0 = 4 * tx;
    const size_t sP = (size_t)NP * NP;
    const size_t prow = (size_t)(z + 1) * sP + (size_t)(y + 1) * NP + 1;

    const float4 C  = ld4u(&pre[prow + gx0]);
    const float4 up = ld4u(&pre[prow - NP + gx0]);
    const float4 dn = ld4u(&pre[prow + NP + gx0]);
    const float4 zm = ld4u(&pre[prow - sP + gx0]);
    const float4 zp = ld4u(&pre[prow + sP + gx0]);
    float4 fv = ld4u(&f[prow + gx0]);
    fv.x *= HHC; fv.y *= HHC; fv.z *= HHC; fv.w *= HHC;

    float lft = __shfl_up(C.w, 1);
    if (tx == 0)  lft = pre[prow + gx0 - 1];
    float rgt = __shfl_down(C.x, 1);
    if (tx == 63) rgt = pre[prow + gx0 + 4];

    float4 o;
    o.x = (lft + C.y + up.x + dn.x + zm.x + zp.x + fv.x) * SIXTH;
    o.y = (C.x + C.z + up.y + dn.y + zm.y + zp.y + fv.y) * SIXTH;
    o.z = (C.y + C.w + up.z + dn.z + zm.z + zp.z + fv.z) * SIXTH;
    o.w = (C.z + rgt + up.w + dn.w + zm.w + zp.w + fv.w) * SIXTH;

    const size_t oi = ((size_t)z * NI + y) * NI + gx0;
    *reinterpret_cast<float4*>(&out[oi]) = o;
    *reinterpret_cast<float4*>(&g[oi])  = fv;
}

// Final single sweep, float4, using g.
__global__ void step_last_v(const float4* __restrict__ u4,
                            const float4* __restrict__ g4,
                            float4* __restrict__ out4) {
    const int tx = threadIdx.x;
    const int y  = blockIdx.y * 4 + threadIdx.y;
    const int z  = blockIdx.z;
    const int rowq   = NI / 4;
    const int planeq = NI * rowq;
    const int r = z * planeq + y * rowq + tx;

    const float4 v = u4[r];
    float left  = __shfl_up(v.w, 1);
    float right = __shfl_down(v.x, 1);
    if (tx == 0)  left  = 0.0f;
    if (tx == 63) right = 0.0f;

    float4 nb;
    nb.x = left + v.y;
    nb.y = v.x  + v.z;
    nb.z = v.y  + v.w;
    nb.w = v.z  + right;

    if (y > 0)      { float4 b = u4[r - rowq];   nb.x += b.x; nb.y += b.y; nb.z += b.z; nb.w += b.w; }
    if (y < NI - 1) { float4 b = u4[r + rowq];   nb.x += b.x; nb.y += b.y; nb.z += b.z; nb.w += b.w; }
    if (z > 0)      { float4 b = u4[r - planeq]; nb.x += b.x; nb.y += b.y; nb.z += b.z; nb.w += b.w; }
    if (z < NI - 1) { float4 b = u4[r + planeq]; nb.x += b.x; nb.y += b.y; nb.z += b.z; nb.w += b.w; }

    const float4 gv = g4[r];
    float4 o;
    o.x = (nb.x + gv.x) * SIXTH;
    o.y = (nb.y + gv.y) * SIXTH;
    o.z = (nb.z + gv.z) * SIXTH;
    o.w = (nb.w + gv.w) * SIXTH;
    out4[r] = o;
}

// Fused double sweep out = J(J(u)), unified-position map with y-pair batching.
// Thread (q,c) owns region rows rr0=2q, rr1=2q+1 (gy = y0-2+rr) and x-chunk c
// (gx = x0-4+4c) for ALL roles:
//  stage:  su[t&1][rr][c] = u(t+2) (from prefetch reg; u_zp comes free from reg)
//  W:      w(t+1) via reg z-ring (u_zm,u_c,u_zp) + LDS {uy|dy boundary, cp, cn}
//          (intra-pair y-neighbor from own regs); writes sw[(t+1)&1]
//  O:      out(t) via reg w-ring + LDS {uy|dy boundary, cp, cn} of sw[t&1]
// All intra-iter slot accesses disjoint -> ONE barrier per z-iteration.
__global__ __launch_bounds__(192, 4)
void step_fused2y(const float* __restrict__ u,
                  const float* __restrict__ g,
                  float* __restrict__ out) {
    __shared__ float4 su[2][36][10];
    __shared__ float4 sw[2][36][10];

    const int tid = threadIdx.x;

    // XCD-contiguous tile remap (grid 8x8x16 = 1024 = 8 XCDs x 128).
    const int lid = blockIdx.x + (blockIdx.y << 3) + (blockIdx.z << 6);
    const int swzid = (lid & 7) * 128 + (lid >> 3);
    const int x0 = (swzid & 7) * TX;
    const int y0 = ((swzid >> 3) & 7) * TY;
    const int z0 = (swzid >> 6) * CZ;
    const int zend = z0 + CZ;
    const int plq = NI * NI;

    const int q = tid / 10, c = tid - q * 10;
    const bool act = q < 18;
    const int rr0 = 2 * q, rr1 = rr0 + 1;
    const int gy0 = y0 - 2 + rr0, gy1 = gy0 + 1;
    const int gxc = x0 - 4 + 4 * c;
    const bool inx = (gxc >= 0 && gxc < NI);
    const bool in0 = act && inx && gy0 >= 0 && gy0 < NI;
    const bool in1 = act && inx && gy1 >= 0 && gy1 < NI;
    const int base0 = gy0 * NI + gxc;
    const int base1 = base0 + NI;

    const bool w0ok = in0 && rr0 >= 1;           // rr0 <= 34 always
    const bool w1ok = in1 && rr1 < 35;           // rr1 >= 1 always
    const bool oc   = (c >= 1 && c < 9);
    const bool o0ok = act && oc && rr0 >= 2 && rr0 < 34;
    const bool o1ok = act && oc && rr1 >= 2 && rr1 < 34;
    const int cmi = (c > 0) ? c - 1 : 0;         // clamped; garbage confined to unused comps
    const int cpi = (c < 9) ? c + 1 : 9;

    // Register rings + prefetch
    float4 ru0 = zero4(), ru1 = zero4();
    float4 u_zm0 = zero4(), u_c0 = zero4(), u_zp0 = zero4();
    float4 u_zm1 = zero4(), u_c1 = zero4(), u_zp1 = zero4();
    float4 w_zm0 = zero4(), w_c0 = zero4(), w_zp0 = zero4();
    float4 w_zm1 = zero4(), w_c1 = zero4(), w_zp1 = zero4();
    float4 g0_0 = zero4(), g0_1 = zero4(), g1_0 = zero4(), g1_1 = zero4();
    float4 gn0 = zero4(), gn1 = zero4();

    // Prologue: u_zp <- u(z0-2), ru <- u(z0-1)  (zero when plane < 0)
    if (z0 - 2 >= 0) {
        if (in0) u_zp0 = ldg4(&u[(size_t)(z0 - 2) * plq + base0]);
        if (in1) u_zp1 = ldg4(&u[(size_t)(z0 - 2) * plq + base1]);
    }
    if (z0 - 1 >= 0) {
        if (in0) ru0 = ldg4(&u[(size_t)(z0 - 1) * plq + base0]);
        if (in1) ru1 = ldg4(&u[(size_t)(z0 - 1) * plq + base1]);
    }

    for (int t = z0 - 3; t < zend; ++t) {
        // ---- stage: su plane t+2 (slot t&1) from ru; ring shift; prefetch u(t+3) ----
        if (act) { su[t & 1][rr0][c] = ru0; su[t & 1][rr1][c] = ru1; }
        u_zm0 = u_c0; u_c0 = u_zp0; u_zp0 = ru0;
        u_zm1 = u_c1; u_c1 = u_zp1; u_zp1 = ru1;
        ru0 = zero4(); ru1 = zero4();
        if (t < zend - 1 && t + 3 < NI) {
            if (in0) ru0 = ldg4(&u[(size_t)(t + 3) * plq + base0]);
            if (in1) ru1 = ldg4(&u[(size_t)(t + 3) * plq + base1]);
        }
        // ---- g ring: g0 = g(t), g1 = g(t+1); prefetch gn = g(t+2) ----
        g0_0 = g1_0; g0_1 = g1_1; g1_0 = gn0; g1_1 = gn1;
        gn0 = zero4(); gn1 = zero4();
        if (t < zend - 1 && t + 2 >= 0 && t + 2 < NI) {
            if (in0) gn0 = ldg4(&g[(size_t)(t + 2) * plq + base0]);
            if (in1) gn1 = ldg4(&g[(size_t)(t + 2) * plq + base1]);
        }

        // ---- W: compute w(t+1) from reg u-ring + su[(t+1)&1] xy-neighbors ----
        const int pw = t + 1;
        float4 wv0 = zero4(), wv1 = zero4();
        if (t >= z0 - 2 && pw >= 0 && pw < NI) {
            const int s1 = pw & 1;
            if (w0ok) {
                const float4 uy  = su[s1][rr0 - 1][c];
                const float4 dy  = u_c1;                      // own reg, row rr1
                const float4 cpv = su[s1][rr0][cmi];
                const float4 cnv = su[s1][rr0][cpi];
                wv0.x = (cpv.w  + u_c0.y + uy.x + dy.x + u_zm0.x + u_zp0.x + g1_0.x) * SIXTH;
                wv0.y = (u_c0.x + u_c0.z + uy.y + dy.y + u_zm0.y + u_zp0.y + g1_0.y) * SIXTH;
                wv0.z = (u_c0.y + u_c0.w + uy.z + dy.z + u_zm0.z + u_zp0.z + g1_0.z) * SIXTH;
                wv0.w = (u_c0.z + cnv.x  + uy.w + dy.w + u_zm0.w + u_zp0.w + g1_0.w) * SIXTH;
            }
            if (w1ok) {
                const float4 uy  = u_c0;                      // own reg, row rr0
                const float4 dy  = su[s1][rr1 + 1][c];
                const float4 cpv = su[s1][rr1][cmi];
                const float4 cnv = su[s1][rr1][cpi];
                wv1.x = (cpv.w  + u_c1.y + uy.x + dy.x + u_zm1.x + u_zp1.x + g1_1.x) * SIXTH;
                wv1.y = (u_c1.x + u_c1.z + uy.y + dy.y + u_zm1.y + u_zp1.y + g1_1.y) * SIXTH;
                wv1.z = (u_c1.y + u_c1.w + uy.z + dy.z + u_zm1.z + u_zp1.z + g1_1.z) * SIXTH;
                wv1.w = (u_c1.z + cnv.x  + uy.w + dy.w + u_zm1.w + u_zp1.w + g1_1.w) * SIXTH;
            }
        }
        w_zm0 = w_c0; w_c0 = w_zp0; w_zp0 = wv0;
        w_zm1 = w_c1; w_c1 = w_zp1; w_zp1 = wv1;
        if (act) { sw[pw & 1][rr0][c] = wv0; sw[pw & 1][rr1][c] = wv1; }

        // ---- O: out(t) from reg w-ring + sw[t&1] xy-neighbors ----
        if (t >= z0) {
            const int s0 = t & 1;
            if (o0ok) {
                const float4 uy  = sw[s0][rr0 - 1][c];
                const float4 dy  = w_c1;                      // own reg, row rr1
                const float4 cpv = sw[s0][rr0][c - 1];
                const float4 cnv = sw[s0][rr0][c + 1];
                float4 ov;
                ov.x = (cpv.w  + w_c0.y + uy.x + dy.x + w_zm0.x + w_zp0.x + g0_0.x) * SIXTH;
                ov.y = (w_c0.x + w_c0.z + uy.y + dy.y + w_zm0.y + w_zp0.y + g0_0.y) * SIXTH;
                ov.z = (w_c0.y + w_c0.w + uy.z + dy.z + w_zm0.z + w_zp0.z + g0_0.z) * SIXTH;
                ov.w = (w_c0.z + cnv.x  + uy.w + dy.w + w_zm0.w + w_zp0.w + g0_0.w) * SIXTH;
                *reinterpret_cast<float4*>(&out[(size_t)t * plq + base0]) = ov;
            }
            if (o1ok) {
                const float4 uy  = w_c0;                      // own reg, row rr0
                const float4 dy  = sw[s0][rr1 + 1][c];
                const float4 cpv = sw[s0][rr1][c - 1];
                const float4 cnv = sw[s0][rr1][c + 1];
                float4 ov;
                ov.x = (cpv.w  + w_c1.y + uy.x + dy.x + w_zm1.x + w_zp1.x + g0_1.x) * SIXTH;
                ov.y = (w_c1.x + w_c1.z + uy.y + dy.y + w_zm1.y + w_zp1.y + g0_1.y) * SIXTH;
                ov.z = (w_c1.y + w_c1.w + uy.z + dy.z + w_zm1.z + w_zp1.z + g0_1.z) * SIXTH;
                ov.w = (w_c1.z + cnv.x  + uy.w + dy.w + w_zm1.w + w_zp1.w + g0_1.w) * SIXTH;
                *reinterpret_cast<float4*>(&out[(size_t)t * plq + base1]) = ov;
            }
        }
        __syncthreads();
    }
}

extern "C" void kernel_launch(void* const* d_in, const int* in_sizes, int n_in,
                              void* d_out, int out_size, void* d_ws, size_t ws_size,
                              hipStream_t stream) {
    const float* pre = (const float*)d_in[0];
    const float* f   = (const float*)d_in[1];
    float* out = (float*)d_out;
    float* buf = (float*)d_ws;
    const size_t nInt = (size_t)NI * NI * NI;
    float* g = buf + nInt;                              // g = h^2*f (ws >= 128 MiB)

    // 20 sweeps: step_first (1) + 9 fused (18) + 1 single.
    step_first_v<<<dim3(1, NI / 4, NI), dim3(64, 4, 1), 0, stream>>>(pre, f, out, g);

    float* cur = out;
    float* nxt = buf;
    dim3 fg(NI / TX, NI / TY, NI / CZ);                 // 8x8x16 = 1024 blocks
    for (int i = 0; i < 9; ++i) {
        step_fused2y<<<fg, dim3(192, 1, 1), 0, stream>>>(cur, g, nxt);
        float* tmp = cur; cur = nxt; nxt = tmp;
    }
    // cur == buf after 9 swaps; final single sweep buf -> out.
    step_last_v<<<dim3(1, NI / 4, NI), dim3(64, 4, 1), 0, stream>>>(
        (const float4*)cur, (const float4*)g, (float4*)out);
}

// Round 12
// 418.075 us; speedup vs baseline: 1.3588x; 1.1123x over previous
//
#include <hip/hip_runtime.h>

// 3D Jacobi (6-neighbor), 20 sweeps, zero-Dirichlet.
// step_first_v (padded pre -> ws + g=h^2*f) + 6x fused TRIPLE-sweeps
// (2.5D z-march; u/w1/w2/g column rings in registers, ring-2 LDS planes for
// xy-exchange, 1 barrier/iter) + 1 single float4 sweep.

#define NP 258
#define NI 256
#define HHC ((1.0f / 257.0f) * (1.0f / 257.0f))
#define SIXTH (1.0f / 6.0f)

#define TX 32
#define TY 32
#define CZ 16
#define NR 38    // region rows: gy in [y0-3, y0+35)
#define NC 10    // f4 x-chunks: gx in [x0-4, x0+36)

__device__ __forceinline__ float4 ld4u(const float* p) {
    float4 v; __builtin_memcpy(&v, p, sizeof(float4)); return v;
}
__device__ __forceinline__ float4 zero4() { return make_float4(0.f, 0.f, 0.f, 0.f); }
__device__ __forceinline__ float4 ldg4(const float* p) {
    return *reinterpret_cast<const float4*>(p);
}

// First sweep, vectorized: padded pre (incl. random halo) -> out, g = h^2*f.
__global__ void step_first_v(const float* __restrict__ pre,
                             const float* __restrict__ f,
                             float* __restrict__ out,
                             float* __restrict__ g) {
    const int tx = threadIdx.x;
    const int y  = blockIdx.y * 4 + threadIdx.y;
    const int z  = blockIdx.z;
    const int gx0 = 4 * tx;
    const size_t sP = (size_t)NP * NP;
    const size_t prow = (size_t)(z + 1) * sP + (size_t)(y + 1) * NP + 1;

    const float4 C  = ld4u(&pre[prow + gx0]);
    const float4 up = ld4u(&pre[prow - NP + gx0]);
    const float4 dn = ld4u(&pre[prow + NP + gx0]);
    const float4 zm = ld4u(&pre[prow - sP + gx0]);
    const float4 zp = ld4u(&pre[prow + sP + gx0]);
    float4 fv = ld4u(&f[prow + gx0]);
    fv.x *= HHC; fv.y *= HHC; fv.z *= HHC; fv.w *= HHC;

    float lft = __shfl_up(C.w, 1);
    if (tx == 0)  lft = pre[prow + gx0 - 1];
    float rgt = __shfl_down(C.x, 1);
    if (tx == 63) rgt = pre[prow + gx0 + 4];

    float4 o;
    o.x = (lft + C.y + up.x + dn.x + zm.x + zp.x + fv.x) * SIXTH;
    o.y = (C.x + C.z + up.y + dn.y + zm.y + zp.y + fv.y) * SIXTH;
    o.z = (C.y + C.w + up.z + dn.z + zm.z + zp.z + fv.z) * SIXTH;
    o.w = (C.z + rgt + up.w + dn.w + zm.w + zp.w + fv.w) * SIXTH;

    const size_t oi = ((size_t)z * NI + y) * NI + gx0;
    *reinterpret_cast<float4*>(&out[oi]) = o;
    *reinterpret_cast<float4*>(&g[oi])  = fv;
}

// Final single sweep, float4, using g.
__global__ void step_last_v(const float4* __restrict__ u4,
                            const float4* __restrict__ g4,
                            float4* __restrict__ out4) {
    const int tx = threadIdx.x;
    const int y  = blockIdx.y * 4 + threadIdx.y;
    const int z  = blockIdx.z;
    const int rowq   = NI / 4;
    const int planeq = NI * rowq;
    const int r = z * planeq + y * rowq + tx;

    const float4 v = u4[r];
    float left  = __shfl_up(v.w, 1);
    float right = __shfl_down(v.x, 1);
    if (tx == 0)  left  = 0.0f;
    if (tx == 63) right = 0.0f;

    float4 nb;
    nb.x = left + v.y;
    nb.y = v.x  + v.z;
    nb.z = v.y  + v.w;
    nb.w = v.z  + right;

    if (y > 0)      { float4 b = u4[r - rowq];   nb.x += b.x; nb.y += b.y; nb.z += b.z; nb.w += b.w; }
    if (y < NI - 1) { float4 b = u4[r + rowq];   nb.x += b.x; nb.y += b.y; nb.z += b.z; nb.w += b.w; }
    if (z > 0)      { float4 b = u4[r - planeq]; nb.x += b.x; nb.y += b.y; nb.z += b.z; nb.w += b.w; }
    if (z < NI - 1) { float4 b = u4[r + planeq]; nb.x += b.x; nb.y += b.y; nb.z += b.z; nb.w += b.w; }

    const float4 gv = g4[r];
    float4 o;
    o.x = (nb.x + gv.x) * SIXTH;
    o.y = (nb.y + gv.y) * SIXTH;
    o.z = (nb.z + gv.z) * SIXTH;
    o.w = (nb.w + gv.w) * SIXTH;
    out4[r] = o;
}

// Fused TRIPLE sweep out = J(J(J(u))), 2.5D pipeline.
// Per iter t: stage su plane t+3; W1 computes w1(t+2) (u-ring regs + su xy);
// W2 computes w2(t+1) (w1-ring + sw1 xy); O stores out(t) (w2-ring + sw2 xy).
// g(t+3) loaded once/iter, flows ring g2->g1->g0 feeding W1/W2/O.
// All intra-iter LDS slot accesses disjoint -> ONE barrier/iter (at end).
__global__ __launch_bounds__(384, 4)
void step_fused3(const float* __restrict__ u,
                 const float* __restrict__ g,
                 float* __restrict__ out) {
    __shared__ float4 su [2][NR][NC];
    __shared__ float4 sw1[2][NR][NC];
    __shared__ float4 sw2[2][NR][NC];

    const int tid = threadIdx.x;

    // XCD-contiguous tile remap (grid 8x8x16 = 1024 = 8 XCDs x 128).
    const int lid = blockIdx.x + (blockIdx.y << 3) + (blockIdx.z << 6);
    const int swzid = (lid & 7) * 128 + (lid >> 3);
    const int x0 = (swzid & 7) * TX;
    const int y0 = ((swzid >> 3) & 7) * TY;
    const int z0 = (swzid >> 6) * CZ;
    const int zend = z0 + CZ;
    const int plq = NI * NI;

    const int r = tid / NC, c = tid - r * NC;
    const bool act = r < NR;                         // tid < 380
    const int gy  = y0 - 3 + r;
    const int gxc = x0 - 4 + 4 * c;
    const bool inr = act && gy >= 0 && gy < NI && gxc >= 0 && gxc < NI;
    const int base = gy * NI + gxc;

    const bool w1ok = inr && r >= 1 && r <= 36;      // w1 rows gy in [y0-2, y0+34)
    const bool w2ok = inr && r >= 2 && r <= 35;      // w2 rows gy in [y0-1, y0+33)
    const bool ook  = act && r >= 3 && r <= 34 && c >= 1 && c <= 8;  // out rows/cols
    const int cmi = (c > 0) ? c - 1 : 0;             // clamped; garbage confined to unused comps
    const int cpi = (c < 9) ? c + 1 : 9;

    // Register rings + prefetch
    float4 ru = zero4(), gn = zero4();
    float4 u_zm  = zero4(), u_c  = zero4(), u_zp  = zero4();
    float4 w1_zm = zero4(), w1_c = zero4(), w1_zp = zero4();
    float4 w2_zm = zero4(), w2_c = zero4(), w2_zp = zero4();
    float4 g0 = zero4(), g1 = zero4(), g2 = zero4();

    // Prologue: u_zp <- u(z0-3), ru <- u(z0-2)  (zeros for planes < 0)
    if (inr) {
        if (z0 - 3 >= 0) u_zp = ldg4(&u[(size_t)(z0 - 3) * plq + base]);
        if (z0 - 2 >= 0) ru   = ldg4(&u[(size_t)(z0 - 2) * plq + base]);
    }

    for (int t = z0 - 5; t < zend; ++t) {
        // ---- stage: su plane t+3 (slot (t+3)&1) from ru; ring shifts; prefetch ----
        if (act) su[(t + 3) & 1][r][c] = ru;
        u_zm = u_c; u_c = u_zp; u_zp = ru;
        g0 = g1; g1 = g2; g2 = gn;
        ru = zero4(); gn = zero4();
        if (t < zend - 1 && inr) {
            if (t + 4 >= 0 && t + 4 < NI)            // FIX: t+4 >= 0 (z0=0 blocks hit t+4 = -1)
                ru = ldg4(&u[(size_t)(t + 4) * plq + base]);
            if (t + 3 >= 0 && t + 3 < NI)
                gn = ldg4(&g[(size_t)(t + 3) * plq + base]);
        }

        // ---- W1: w1(t+2) from u-ring (zm,c,zp) + su[(t+2)&1] xy + g2 ----
        const int pw1 = t + 2;
        float4 wv1 = zero4();
        if (t >= z0 - 4 && pw1 >= 0 && pw1 < NI && w1ok) {
            const int s = pw1 & 1;
            const float4 uy = su[s][r - 1][c];
            const float4 dy = su[s][r + 1][c];
            const float4 cp = su[s][r][cmi];
            const float4 cn = su[s][r][cpi];
            wv1.x = (cp.w  + u_c.y + uy.x + dy.x + u_zm.x + u_zp.x + g2.x) * SIXTH;
            wv1.y = (u_c.x + u_c.z + uy.y + dy.y + u_zm.y + u_zp.y + g2.y) * SIXTH;
            wv1.z = (u_c.y + u_c.w + uy.z + dy.z + u_zm.z + u_zp.z + g2.z) * SIXTH;
            wv1.w = (u_c.z + cn.x  + uy.w + dy.w + u_zm.w + u_zp.w + g2.w) * SIXTH;
        }
        if (act) sw1[(t + 2) & 1][r][c] = wv1;
        w1_zm = w1_c; w1_c = w1_zp; w1_zp = wv1;     // now w1_c = w1(t+1), w1_zm = w1(t)

        // ---- W2: w2(t+1) from w1-ring + sw1[(t+1)&1] xy + g1 ----
        const int pw2 = t + 1;
        float4 wv2 = zero4();
        if (t >= z0 - 2 && pw2 >= 0 && pw2 < NI && w2ok) {
            const int s = pw2 & 1;
            const float4 uy = sw1[s][r - 1][c];
            const float4 dy = sw1[s][r + 1][c];
            const float4 cp = sw1[s][r][cmi];
            const float4 cn = sw1[s][r][cpi];
            wv2.x = (cp.w   + w1_c.y + uy.x + dy.x + w1_zm.x + w1_zp.x + g1.x) * SIXTH;
            wv2.y = (w1_c.x + w1_c.z + uy.y + dy.y + w1_zm.y + w1_zp.y + g1.y) * SIXTH;
            wv2.z = (w1_c.y + w1_c.w + uy.z + dy.z + w1_zm.z + w1_zp.z + g1.z) * SIXTH;
            wv2.w = (w1_c.z + cn.x   + uy.w + dy.w + w1_zm.w + w1_zp.w + g1.w) * SIXTH;
        }
        if (act) sw2[(t + 1) & 1][r][c] = wv2;
        w2_zm = w2_c; w2_c = w2_zp; w2_zp = wv2;     // now w2_c = w2(t), w2_zm = w2(t-1)

        // ---- O: out(t) from w2-ring + sw2[t&1] xy + g0 ----
        if (t >= z0 && ook) {
            const int s = t & 1;
            const float4 uy = sw2[s][r - 1][c];
            const float4 dy = sw2[s][r + 1][c];
            const float4 cp = sw2[s][r][c - 1];
            const float4 cn = sw2[s][r][c + 1];
            float4 ov;
            ov.x = (cp.w   + w2_c.y + uy.x + dy.x + w2_zm.x + w2_zp.x + g0.x) * SIXTH;
            ov.y = (w2_c.x + w2_c.z + uy.y + dy.y + w2_zm.y + w2_zp.y + g0.y) * SIXTH;
            ov.z = (w2_c.y + w2_c.w + uy.z + dy.z + w2_zm.z + w2_zp.z + g0.z) * SIXTH;
            ov.w = (w2_c.z + cn.x   + uy.w + dy.w + w2_zm.w + w2_zp.w + g0.w) * SIXTH;
            *reinterpret_cast<float4*>(&out[(size_t)t * plq + base]) = ov;
        }
        __syncthreads();   // single barrier: separates this iter's LDS writes
                           // from next iter's reads (all intra-iter slots disjoint)
    }
}

extern "C" void kernel_launch(void* const* d_in, const int* in_sizes, int n_in,
                              void* d_out, int out_size, void* d_ws, size_t ws_size,
                              hipStream_t stream) {
    const float* pre = (const float*)d_in[0];
    const float* f   = (const float*)d_in[1];
    float* out = (float*)d_out;
    float* buf = (float*)d_ws;
    const size_t nInt = (size_t)NI * NI * NI;
    float* g = buf + nInt;                           // g = h^2*f (ws >= 128 MiB)

    // 20 sweeps: step_first (1) + 6 fused triple (18) + 1 single.
    // first -> buf; P1 buf->out, P2 out->buf, ... P6 out->buf; last buf->out.
    step_first_v<<<dim3(1, NI / 4, NI), dim3(64, 4, 1), 0, stream>>>(pre, f, buf, g);

    float* cur = buf;
    float* nxt = out;
    dim3 fg(NI / TX, NI / TY, NI / CZ);              // 8x8x16 = 1024 blocks
    for (int i = 0; i < 6; ++i) {
        step_fused3<<<fg, dim3(384, 1, 1), 0, stream>>>(cur, g, nxt);
        float* tmp = cur; cur = nxt; nxt = tmp;
    }
    // cur == buf after 6 swaps; final single sweep buf -> out.
    step_last_v<<<dim3(1, NI / 4, NI), dim3(64, 4, 1), 0, stream>>>(
        (const float4*)cur, (const float4*)g, (float4*)out);
}

// Round 14
// 391.116 us; speedup vs baseline: 1.4524x; 1.0689x over previous
//
#include <hip/hip_runtime.h>

// 3D Jacobi (6-neighbor), 20 sweeps, zero-Dirichlet.
// step_first_v (padded pre -> ws + g=h^2*f) + 6x fused TRIPLE-sweeps
// (2.5D z-march; x-PAIR threads: 2 adjacent f4 chunks/thread, u/w1/w2/g
// register rings, ring-2 LDS planes, linear 32B-stride LDS addressing,
// 1 barrier/iter) + 1 single float4 sweep.

#define NP 258
#define NI 256
#define HHC ((1.0f / 257.0f) * (1.0f / 257.0f))
#define SIXTH (1.0f / 6.0f)

#define TX 32
#define TY 32
#define CZ 16
#define NR 38    // region rows: gy in [y0-3, y0+35)
#define NC 10    // f4 x-chunks: gx in [x0-4, x0+36)

__device__ __forceinline__ float4 ld4u(const float* p) {
    float4 v; __builtin_memcpy(&v, p, sizeof(float4)); return v;
}
__device__ __forceinline__ float4 zero4() { return make_float4(0.f, 0.f, 0.f, 0.f); }
__device__ __forceinline__ float4 ldg4(const float* p) {
    return *reinterpret_cast<const float4*>(p);
}

// First sweep, vectorized: padded pre (incl. random halo) -> out, g = h^2*f.
__global__ void step_first_v(const float* __restrict__ pre,
                             const float* __restrict__ f,
                             float* __restrict__ out,
                             float* __restrict__ g) {
    const int tx = threadIdx.x;
    const int y  = blockIdx.y * 4 + threadIdx.y;
    const int z  = blockIdx.z;
    const int gx0 = 4 * tx;
    const size_t sP = (size_t)NP * NP;
    const size_t prow = (size_t)(z + 1) * sP + (size_t)(y + 1) * NP + 1;

    const float4 C  = ld4u(&pre[prow + gx0]);
    const float4 up = ld4u(&pre[prow - NP + gx0]);
    const float4 dn = ld4u(&pre[prow + NP + gx0]);
    const float4 zm = ld4u(&pre[prow - sP + gx0]);
    const float4 zp = ld4u(&pre[prow + sP + gx0]);
    float4 fv = ld4u(&f[prow + gx0]);
    fv.x *= HHC; fv.y *= HHC; fv.z *= HHC; fv.w *= HHC;

    float lft = __shfl_up(C.w, 1);
    if (tx == 0)  lft = pre[prow + gx0 - 1];
    float rgt = __shfl_down(C.x, 1);
    if (tx == 63) rgt = pre[prow + gx0 + 4];

    float4 o;
    o.x = (lft + C.y + up.x + dn.x + zm.x + zp.x + fv.x) * SIXTH;
    o.y = (C.x + C.z + up.y + dn.y + zm.y + zp.y + fv.y) * SIXTH;
    o.z = (C.y + C.w + up.z + dn.z + zm.z + zp.z + fv.z) * SIXTH;
    o.w = (C.z + rgt + up.w + dn.w + zm.w + zp.w + fv.w) * SIXTH;

    const size_t oi = ((size_t)z * NI + y) * NI + gx0;
    *reinterpret_cast<float4*>(&out[oi]) = o;
    *reinterpret_cast<float4*>(&g[oi])  = fv;
}

// Final single sweep, float4, using g.
__global__ void step_last_v(const float4* __restrict__ u4,
                            const float4* __restrict__ g4,
                            float4* __restrict__ out4) {
    const int tx = threadIdx.x;
    const int y  = blockIdx.y * 4 + threadIdx.y;
    const int z  = blockIdx.z;
    const int rowq   = NI / 4;
    const int planeq = NI * rowq;
    const int r = z * planeq + y * rowq + tx;

    const float4 v = u4[r];
    float left  = __shfl_up(v.w, 1);
    float right = __shfl_down(v.x, 1);
    if (tx == 0)  left  = 0.0f;
    if (tx == 63) right = 0.0f;

    float4 nb;
    nb.x = left + v.y;
    nb.y = v.x  + v.z;
    nb.z = v.y  + v.w;
    nb.w = v.z  + right;

    if (y > 0)      { float4 b = u4[r - rowq];   nb.x += b.x; nb.y += b.y; nb.z += b.z; nb.w += b.w; }
    if (y < NI - 1) { float4 b = u4[r + rowq];   nb.x += b.x; nb.y += b.y; nb.z += b.z; nb.w += b.w; }
    if (z > 0)      { float4 b = u4[r - planeq]; nb.x += b.x; nb.y += b.y; nb.z += b.z; nb.w += b.w; }
    if (z < NI - 1) { float4 b = u4[r + planeq]; nb.x += b.x; nb.y += b.y; nb.z += b.z; nb.w += b.w; }

    const float4 gv = g4[r];
    float4 o;
    o.x = (nb.x + gv.x) * SIXTH;
    o.y = (nb.y + gv.y) * SIXTH;
    o.z = (nb.z + gv.z) * SIXTH;
    o.w = (nb.w + gv.w) * SIXTH;
    out4[r] = o;
}

// Fused TRIPLE sweep out = J(J(J(u))), x-pair threads.
// Thread (rp, xp): row rp (gy = y0-3+rp), chunks c0=2xp, c1=2xp+1.
// Intra-pair x-neighbors from registers; LDS supplies {uy,dy}x2 + {cp,cn}x1
// per stage. Same z-pipeline/guards as verified R12 kernel.
__global__ __launch_bounds__(192, 3)
void step_fused3x(const float* __restrict__ u,
                  const float* __restrict__ g,
                  float* __restrict__ out) {
    __shared__ float4 su [2][NR][NC];
    __shared__ float4 sw1[2][NR][NC];
    __shared__ float4 sw2[2][NR][NC];

    const int tid = threadIdx.x;

    // XCD-contiguous tile remap (grid 8x8x16 = 1024 = 8 XCDs x 128).
    const int lid = blockIdx.x + (blockIdx.y << 3) + (blockIdx.z << 6);
    const int swzid = (lid & 7) * 128 + (lid >> 3);
    const int x0 = (swzid & 7) * TX;
    const int y0 = ((swzid >> 3) & 7) * TY;
    const int z0 = (swzid >> 6) * CZ;
    const int zend = z0 + CZ;
    const int plq = NI * NI;

    const int rp = tid / 5, xp = tid - rp * 5;
    const bool act = rp < NR;                        // tid < 190
    const int c0 = 2 * xp, c1 = c0 + 1;
    const int gy  = y0 - 3 + rp;
    const int gx0c = x0 - 4 + 4 * c0;
    const int gx1c = gx0c + 4;                       // = x0 + 8*xp
    const bool gyok = act && gy >= 0 && gy < NI;
    const bool in0 = gyok && gx0c >= 0 && gx0c < NI;
    const bool in1 = gyok && gx1c < NI;              // FIX: right-halo chunk of last tile (gx1c=256) is OOB
    const int base0 = gy * NI + gx0c;
    const int base1 = base0 + 4;

    const bool row_w1 = rp >= 1 && rp <= 36;
    const bool row_w2 = rp >= 2 && rp <= 35;
    const bool row_o  = act && rp >= 3 && rp <= 34;
    const bool w1ok0 = in0 && row_w1, w1ok1 = in1 && row_w1;
    const bool w2ok0 = in0 && row_w2, w2ok1 = in1 && row_w2;
    const bool ook0  = row_o && c0 >= 1 && c0 <= 8;  // xp>=1
    const bool ook1  = row_o && c1 <= 8;             // xp<=3
    const int cmi = (c0 > 0) ? c0 - 1 : 0;           // left of pair; clamp garbage confined
    const int cpi = (c1 < 9) ? c1 + 1 : 9;           // right of pair

    // Register rings (per chunk) + prefetch
    float4 ru0 = zero4(), ru1 = zero4(), gn0 = zero4(), gn1 = zero4();
    float4 u_zm0 = zero4(), u_c0 = zero4(), u_zp0 = zero4();
    float4 u_zm1 = zero4(), u_c1 = zero4(), u_zp1 = zero4();
    float4 w1_zm0 = zero4(), w1_c0 = zero4(), w1_zp0 = zero4();
    float4 w1_zm1 = zero4(), w1_c1 = zero4(), w1_zp1 = zero4();
    float4 w2_zm0 = zero4(), w2_c0 = zero4(), w2_zp0 = zero4();
    float4 w2_zm1 = zero4(), w2_c1 = zero4(), w2_zp1 = zero4();
    float4 g0_0 = zero4(), g0_1 = zero4(), g1_0 = zero4(), g1_1 = zero4();
    float4 g2_0 = zero4(), g2_1 = zero4();

    // Prologue: u_zp <- u(z0-3), ru <- u(z0-2)  (zeros for planes < 0)
    if (z0 - 3 >= 0) {
        if (in0) u_zp0 = ldg4(&u[(size_t)(z0 - 3) * plq + base0]);
        if (in1) u_zp1 = ldg4(&u[(size_t)(z0 - 3) * plq + base1]);
    }
    if (z0 - 2 >= 0) {
        if (in0) ru0 = ldg4(&u[(size_t)(z0 - 2) * plq + base0]);
        if (in1) ru1 = ldg4(&u[(size_t)(z0 - 2) * plq + base1]);
    }

    for (int t = z0 - 5; t < zend; ++t) {
        // ---- stage: su plane t+3 (slot (t+3)&1); ring shifts; prefetch u(t+4), g(t+3) ----
        if (act) { su[(t + 3) & 1][rp][c0] = ru0; su[(t + 3) & 1][rp][c1] = ru1; }
        u_zm0 = u_c0; u_c0 = u_zp0; u_zp0 = ru0;
        u_zm1 = u_c1; u_c1 = u_zp1; u_zp1 = ru1;
        g0_0 = g1_0; g0_1 = g1_1; g1_0 = g2_0; g1_1 = g2_1; g2_0 = gn0; g2_1 = gn1;
        ru0 = zero4(); ru1 = zero4(); gn0 = zero4(); gn1 = zero4();
        if (t < zend - 1) {
            if (t + 4 >= 0 && t + 4 < NI) {
                if (in0) ru0 = ldg4(&u[(size_t)(t + 4) * plq + base0]);
                if (in1) ru1 = ldg4(&u[(size_t)(t + 4) * plq + base1]);
            }
            if (t + 3 >= 0 && t + 3 < NI) {
                if (in0) gn0 = ldg4(&g[(size_t)(t + 3) * plq + base0]);
                if (in1) gn1 = ldg4(&g[(size_t)(t + 3) * plq + base1]);
            }
        }

        // ---- W1: w1(t+2) from u-ring + su[(t+2)&1] {uy,dy,cp,cn} + g2 ----
        const int pw1 = t + 2;
        float4 wv10 = zero4(), wv11 = zero4();
        if (t >= z0 - 4 && pw1 >= 0 && pw1 < NI) {
            const int s = pw1 & 1;
            if (w1ok0) {
                const float4 uy = su[s][rp - 1][c0];
                const float4 dy = su[s][rp + 1][c0];
                const float4 cp = su[s][rp][cmi];
                wv10.x = (cp.w   + u_c0.y + uy.x + dy.x + u_zm0.x + u_zp0.x + g2_0.x) * SIXTH;
                wv10.y = (u_c0.x + u_c0.z + uy.y + dy.y + u_zm0.y + u_zp0.y + g2_0.y) * SIXTH;
                wv10.z = (u_c0.y + u_c0.w + uy.z + dy.z + u_zm0.z + u_zp0.z + g2_0.z) * SIXTH;
                wv10.w = (u_c0.z + u_c1.x + uy.w + dy.w + u_zm0.w + u_zp0.w + g2_0.w) * SIXTH;
            }
            if (w1ok1) {
                const float4 uy = su[s][rp - 1][c1];
                const float4 dy = su[s][rp + 1][c1];
                const float4 cn = su[s][rp][cpi];
                wv11.x = (u_c0.w + u_c1.y + uy.x + dy.x + u_zm1.x + u_zp1.x + g2_1.x) * SIXTH;
                wv11.y = (u_c1.x + u_c1.z + uy.y + dy.y + u_zm1.y + u_zp1.y + g2_1.y) * SIXTH;
                wv11.z = (u_c1.y + u_c1.w + uy.z + dy.z + u_zm1.z + u_zp1.z + g2_1.z) * SIXTH;
                wv11.w = (u_c1.z + cn.x   + uy.w + dy.w + u_zm1.w + u_zp1.w + g2_1.w) * SIXTH;
            }
        }
        if (act) { sw1[(t + 2) & 1][rp][c0] = wv10; sw1[(t + 2) & 1][rp][c1] = wv11; }
        w1_zm0 = w1_c0; w1_c0 = w1_zp0; w1_zp0 = wv10;
        w1_zm1 = w1_c1; w1_c1 = w1_zp1; w1_zp1 = wv11;

        // ---- W2: w2(t+1) from w1-ring + sw1[(t+1)&1] + g1 ----
        const int pw2 = t + 1;
        float4 wv20 = zero4(), wv21 = zero4();
        if (t >= z0 - 2 && pw2 >= 0 && pw2 < NI) {
            const int s = pw2 & 1;
            if (w2ok0) {
                const float4 uy = sw1[s][rp - 1][c0];
                const float4 dy = sw1[s][rp + 1][c0];
                const float4 cp = sw1[s][rp][cmi];
                wv20.x = (cp.w    + w1_c0.y + uy.x + dy.x + w1_zm0.x + w1_zp0.x + g1_0.x) * SIXTH;
                wv20.y = (w1_c0.x + w1_c0.z + uy.y + dy.y + w1_zm0.y + w1_zp0.y + g1_0.y) * SIXTH;
                wv20.z = (w1_c0.y + w1_c0.w + uy.z + dy.z + w1_zm0.z + w1_zp0.z + g1_0.z) * SIXTH;
                wv20.w = (w1_c0.z + w1_c1.x + uy.w + dy.w + w1_zm0.w + w1_zp0.w + g1_0.w) * SIXTH;
            }
            if (w2ok1) {
                const float4 uy = sw1[s][rp - 1][c1];
                const float4 dy = sw1[s][rp + 1][c1];
                const float4 cn = sw1[s][rp][cpi];
                wv21.x = (w1_c0.w + w1_c1.y + uy.x + dy.x + w1_zm1.x + w1_zp1.x + g1_1.x) * SIXTH;
                wv21.y = (w1_c1.x + w1_c1.z + uy.y + dy.y + w1_zm1.y + w1_zp1.y + g1_1.y) * SIXTH;
                wv21.z = (w1_c1.y + w1_c1.w + uy.z + dy.z + w1_zm1.z + w1_zp1.z + g1_1.z) * SIXTH;
                wv21.w = (w1_c1.z + cn.x    + uy.w + dy.w + w1_zm1.w + w1_zp1.w + g1_1.w) * SIXTH;
            }
        }
        if (act) { sw2[(t + 1) & 1][rp][c0] = wv20; sw2[(t + 1) & 1][rp][c1] = wv21; }
        w2_zm0 = w2_c0; w2_c0 = w2_zp0; w2_zp0 = wv20;
        w2_zm1 = w2_c1; w2_c1 = w2_zp1; w2_zp1 = wv21;

        // ---- O: out(t) from w2-ring + sw2[t&1] + g0 ----
        if (t >= z0) {
            const int s = t & 1;
            if (ook0) {
                const float4 uy = sw2[s][rp - 1][c0];
                const float4 dy = sw2[s][rp + 1][c0];
                const float4 cp = sw2[s][rp][c0 - 1];
                float4 ov;
                ov.x = (cp.w    + w2_c0.y + uy.x + dy.x + w2_zm0.x + w2_zp0.x + g0_0.x) * SIXTH;
                ov.y = (w2_c0.x + w2_c0.z + uy.y + dy.y + w2_zm0.y + w2_zp0.y + g0_0.y) * SIXTH;
                ov.z = (w2_c0.y + w2_c0.w + uy.z + dy.z + w2_zm0.z + w2_zp0.z + g0_0.z) * SIXTH;
                ov.w = (w2_c0.z + w2_c1.x + uy.w + dy.w + w2_zm0.w + w2_zp0.w + g0_0.w) * SIXTH;
                *reinterpret_cast<float4*>(&out[(size_t)t * plq + base0]) = ov;
            }
            if (ook1) {
                const float4 uy = sw2[s][rp - 1][c1];
                const float4 dy = sw2[s][rp + 1][c1];
                const float4 cn = sw2[s][rp][c1 + 1];
                float4 ov;
                ov.x = (w2_c0.w + w2_c1.y + uy.x + dy.x + w2_zm1.x + w2_zp1.x + g0_1.x) * SIXTH;
                ov.y = (w2_c1.x + w2_c1.z + uy.y + dy.y + w2_zm1.y + w2_zp1.y + g0_1.y) * SIXTH;
                ov.z = (w2_c1.y + w2_c1.w + uy.z + dy.z + w2_zm1.z + w2_zp1.z + g0_1.z) * SIXTH;
                ov.w = (w2_c1.z + cn.x    + uy.w + dy.w + w2_zm1.w + w2_zp1.w + g0_1.w) * SIXTH;
                *reinterpret_cast<float4*>(&out[(size_t)t * plq + base1]) = ov;
            }
        }
        __syncthreads();   // single barrier/iter (intra-iter slots disjoint)
    }
}

extern "C" void kernel_launch(void* const* d_in, const int* in_sizes, int n_in,
                              void* d_out, int out_size, void* d_ws, size_t ws_size,
                              hipStream_t stream) {
    const float* pre = (const float*)d_in[0];
    const float* f   = (const float*)d_in[1];
    float* out = (float*)d_out;
    float* buf = (float*)d_ws;
    const size_t nInt = (size_t)NI * NI * NI;
    float* g = buf + nInt;                           // g = h^2*f (ws >= 128 MiB)

    // 20 sweeps: step_first (1) + 6 fused triple (18) + 1 single.
    // first -> buf; P1 buf->out, ... P6 out->buf; last buf->out.
    step_first_v<<<dim3(1, NI / 4, NI), dim3(64, 4, 1), 0, stream>>>(pre, f, buf, g);

    float* cur = buf;
    float* nxt = out;
    dim3 fg(NI / TX, NI / TY, NI / CZ);              // 8x8x16 = 1024 blocks
    for (int i = 0; i < 6; ++i) {
        step_fused3x<<<fg, dim3(192, 1, 1), 0, stream>>>(cur, g, nxt);
        float* tmp = cur; cur = nxt; nxt = tmp;
    }
    // cur == buf after 6 swaps; final single sweep buf -> out.
    step_last_v<<<dim3(1, NI / 4, NI), dim3(64, 4, 1), 0, stream>>>(
        (const float4*)cur, (const float4*)g, (float4*)out);
}

// Round 15
// 380.612 us; speedup vs baseline: 1.4925x; 1.0276x over previous
//
#include <hip/hip_runtime.h>

// 3D Jacobi (6-neighbor), 20 sweeps, zero-Dirichlet.
// step_first_v (padded pre -> ws + g=h^2*f) + 6x fused TRIPLE-sweeps
// (2.5D z-march; x-PAIR threads with bank-permuted LDS columns:
// perm(c)=(c&1)*5+(c>>1) restores uniform bank coverage while keeping
// pair-register adjacency; u/w1/w2/g register rings, ring-2 LDS planes,
// 1 barrier/iter) + 1 single float4 sweep.

#define NP 258
#define NI 256
#define HHC ((1.0f / 257.0f) * (1.0f / 257.0f))
#define SIXTH (1.0f / 6.0f)

#define TX 32
#define TY 32
#define CZ 16
#define NR 38    // region rows: gy in [y0-3, y0+35)
#define NC 10    // f4 x-chunks: gx in [x0-4, x0+36)

__device__ __forceinline__ float4 ld4u(const float* p) {
    float4 v; __builtin_memcpy(&v, p, sizeof(float4)); return v;
}
__device__ __forceinline__ float4 zero4() { return make_float4(0.f, 0.f, 0.f, 0.f); }
__device__ __forceinline__ float4 ldg4(const float* p) {
    return *reinterpret_cast<const float4*>(p);
}
__device__ __forceinline__ int permc(int c) { return (c & 1) * 5 + (c >> 1); }

// First sweep, vectorized: padded pre (incl. random halo) -> out, g = h^2*f.
__global__ void step_first_v(const float* __restrict__ pre,
                             const float* __restrict__ f,
                             float* __restrict__ out,
                             float* __restrict__ g) {
    const int tx = threadIdx.x;
    const int y  = blockIdx.y * 4 + threadIdx.y;
    const int z  = blockIdx.z;
    const int gx0 = 4 * tx;
    const size_t sP = (size_t)NP * NP;
    const size_t prow = (size_t)(z + 1) * sP + (size_t)(y + 1) * NP + 1;

    const float4 C  = ld4u(&pre[prow + gx0]);
    const float4 up = ld4u(&pre[prow - NP + gx0]);
    const float4 dn = ld4u(&pre[prow + NP + gx0]);
    const float4 zm = ld4u(&pre[prow - sP + gx0]);
    const float4 zp = ld4u(&pre[prow + sP + gx0]);
    float4 fv = ld4u(&f[prow + gx0]);
    fv.x *= HHC; fv.y *= HHC; fv.z *= HHC; fv.w *= HHC;

    float lft = __shfl_up(C.w, 1);
    if (tx == 0)  lft = pre[prow + gx0 - 1];
    float rgt = __shfl_down(C.x, 1);
    if (tx == 63) rgt = pre[prow + gx0 + 4];

    float4 o;
    o.x = (lft + C.y + up.x + dn.x + zm.x + zp.x + fv.x) * SIXTH;
    o.y = (C.x + C.z + up.y + dn.y + zm.y + zp.y + fv.y) * SIXTH;
    o.z = (C.y + C.w + up.z + dn.z + zm.z + zp.z + fv.z) * SIXTH;
    o.w = (C.z + rgt + up.w + dn.w + zm.w + zp.w + fv.w) * SIXTH;

    const size_t oi = ((size_t)z * NI + y) * NI + gx0;
    *reinterpret_cast<float4*>(&out[oi]) = o;
    *reinterpret_cast<float4*>(&g[oi])  = fv;
}

// Final single sweep, float4, using g.
__global__ void step_last_v(const float4* __restrict__ u4,
                            const float4* __restrict__ g4,
                            float4* __restrict__ out4) {
    const int tx = threadIdx.x;
    const int y  = blockIdx.y * 4 + threadIdx.y;
    const int z  = blockIdx.z;
    const int rowq   = NI / 4;
    const int planeq = NI * rowq;
    const int r = z * planeq + y * rowq + tx;

    const float4 v = u4[r];
    float left  = __shfl_up(v.w, 1);
    float right = __shfl_down(v.x, 1);
    if (tx == 0)  left  = 0.0f;
    if (tx == 63) right = 0.0f;

    float4 nb;
    nb.x = left + v.y;
    nb.y = v.x  + v.z;
    nb.z = v.y  + v.w;
    nb.w = v.z  + right;

    if (y > 0)      { float4 b = u4[r - rowq];   nb.x += b.x; nb.y += b.y; nb.z += b.z; nb.w += b.w; }
    if (y < NI - 1) { float4 b = u4[r + rowq];   nb.x += b.x; nb.y += b.y; nb.z += b.z; nb.w += b.w; }
    if (z > 0)      { float4 b = u4[r - planeq]; nb.x += b.x; nb.y += b.y; nb.z += b.z; nb.w += b.w; }
    if (z < NI - 1) { float4 b = u4[r + planeq]; nb.x += b.x; nb.y += b.y; nb.z += b.z; nb.w += b.w; }

    const float4 gv = g4[r];
    float4 o;
    o.x = (nb.x + gv.x) * SIXTH;
    o.y = (nb.y + gv.y) * SIXTH;
    o.z = (nb.z + gv.z) * SIXTH;
    o.w = (nb.w + gv.w) * SIXTH;
    out4[r] = o;
}

// Fused TRIPLE sweep out = J(J(J(u))), x-pair threads, permuted LDS columns.
__global__ __launch_bounds__(192, 3)
void step_fused3x(const float* __restrict__ u,
                  const float* __restrict__ g,
                  float* __restrict__ out) {
    __shared__ float4 su [2][NR][NC];
    __shared__ float4 sw1[2][NR][NC];
    __shared__ float4 sw2[2][NR][NC];

    const int tid = threadIdx.x;

    // XCD-contiguous tile remap (grid 8x8x16 = 1024 = 8 XCDs x 128).
    const int lid = blockIdx.x + (blockIdx.y << 3) + (blockIdx.z << 6);
    const int swzid = (lid & 7) * 128 + (lid >> 3);
    const int x0 = (swzid & 7) * TX;
    const int y0 = ((swzid >> 3) & 7) * TY;
    const int z0 = (swzid >> 6) * CZ;
    const int zend = z0 + CZ;
    const int plq = NI * NI;

    const int rp = tid / 5, xp = tid - rp * 5;
    const bool act = rp < NR;                        // tid < 190
    const int c0 = 2 * xp, c1 = c0 + 1;
    const int gy  = y0 - 3 + rp;
    const int gx0c = x0 - 4 + 4 * c0;
    const int gx1c = gx0c + 4;                       // = x0 + 8*xp
    const bool gyok = act && gy >= 0 && gy < NI;
    const bool in0 = gyok && gx0c >= 0 && gx0c < NI;
    const bool in1 = gyok && gx1c < NI;              // right-halo chunk of last tile is OOB
    const int base0 = gy * NI + gx0c;
    const int base1 = base0 + 4;

    // permuted LDS columns (even chunks -> 0..4, odd -> 5..9)
    const int pc0 = xp;                              // permc(c0)
    const int pc1 = 5 + xp;                          // permc(c1)
    const int pcm = permc((c0 > 0) ? c0 - 1 : 0);    // left neighbor of pair (clamped)
    const int pcp = permc((c1 < 9) ? c1 + 1 : 9);    // right neighbor of pair (clamped)

    const bool row_w1 = rp >= 1 && rp <= 36;
    const bool row_w2 = rp >= 2 && rp <= 35;
    const bool row_o  = act && rp >= 3 && rp <= 34;
    const bool w1ok0 = in0 && row_w1, w1ok1 = in1 && row_w1;
    const bool w2ok0 = in0 && row_w2, w2ok1 = in1 && row_w2;
    const bool ook0  = row_o && c0 >= 1 && c0 <= 8;  // xp>=1
    const bool ook1  = row_o && c1 <= 8;             // xp<=3

    // Register rings (per chunk) + prefetch
    float4 ru0 = zero4(), ru1 = zero4(), gn0 = zero4(), gn1 = zero4();
    float4 u_zm0 = zero4(), u_c0 = zero4(), u_zp0 = zero4();
    float4 u_zm1 = zero4(), u_c1 = zero4(), u_zp1 = zero4();
    float4 w1_zm0 = zero4(), w1_c0 = zero4(), w1_zp0 = zero4();
    float4 w1_zm1 = zero4(), w1_c1 = zero4(), w1_zp1 = zero4();
    float4 w2_zm0 = zero4(), w2_c0 = zero4(), w2_zp0 = zero4();
    float4 w2_zm1 = zero4(), w2_c1 = zero4(), w2_zp1 = zero4();
    float4 g0_0 = zero4(), g0_1 = zero4(), g1_0 = zero4(), g1_1 = zero4();
    float4 g2_0 = zero4(), g2_1 = zero4();

    // Prologue: u_zp <- u(z0-3), ru <- u(z0-2)  (zeros for planes < 0)
    if (z0 - 3 >= 0) {
        if (in0) u_zp0 = ldg4(&u[(size_t)(z0 - 3) * plq + base0]);
        if (in1) u_zp1 = ldg4(&u[(size_t)(z0 - 3) * plq + base1]);
    }
    if (z0 - 2 >= 0) {
        if (in0) ru0 = ldg4(&u[(size_t)(z0 - 2) * plq + base0]);
        if (in1) ru1 = ldg4(&u[(size_t)(z0 - 2) * plq + base1]);
    }

    for (int t = z0 - 5; t < zend; ++t) {
        // ---- stage: su plane t+3 (slot (t+3)&1); ring shifts; prefetch u(t+4), g(t+3) ----
        if (act) { su[(t + 3) & 1][rp][pc0] = ru0; su[(t + 3) & 1][rp][pc1] = ru1; }
        u_zm0 = u_c0; u_c0 = u_zp0; u_zp0 = ru0;
        u_zm1 = u_c1; u_c1 = u_zp1; u_zp1 = ru1;
        g0_0 = g1_0; g0_1 = g1_1; g1_0 = g2_0; g1_1 = g2_1; g2_0 = gn0; g2_1 = gn1;
        ru0 = zero4(); ru1 = zero4(); gn0 = zero4(); gn1 = zero4();
        if (t < zend - 1) {
            if (t + 4 >= 0 && t + 4 < NI) {
                if (in0) ru0 = ldg4(&u[(size_t)(t + 4) * plq + base0]);
                if (in1) ru1 = ldg4(&u[(size_t)(t + 4) * plq + base1]);
            }
            if (t + 3 >= 0 && t + 3 < NI) {
                if (in0) gn0 = ldg4(&g[(size_t)(t + 3) * plq + base0]);
                if (in1) gn1 = ldg4(&g[(size_t)(t + 3) * plq + base1]);
            }
        }

        // ---- W1: w1(t+2) from u-ring + su[(t+2)&1] {uy,dy,cp,cn} + g2 ----
        const int pw1 = t + 2;
        float4 wv10 = zero4(), wv11 = zero4();
        if (t >= z0 - 4 && pw1 >= 0 && pw1 < NI) {
            const int s = pw1 & 1;
            if (w1ok0) {
                const float4 uy = su[s][rp - 1][pc0];
                const float4 dy = su[s][rp + 1][pc0];
                const float4 cp = su[s][rp][pcm];
                wv10.x = (cp.w   + u_c0.y + uy.x + dy.x + u_zm0.x + u_zp0.x + g2_0.x) * SIXTH;
                wv10.y = (u_c0.x + u_c0.z + uy.y + dy.y + u_zm0.y + u_zp0.y + g2_0.y) * SIXTH;
                wv10.z = (u_c0.y + u_c0.w + uy.z + dy.z + u_zm0.z + u_zp0.z + g2_0.z) * SIXTH;
                wv10.w = (u_c0.z + u_c1.x + uy.w + dy.w + u_zm0.w + u_zp0.w + g2_0.w) * SIXTH;
            }
            if (w1ok1) {
                const float4 uy = su[s][rp - 1][pc1];
                const float4 dy = su[s][rp + 1][pc1];
                const float4 cn = su[s][rp][pcp];
                wv11.x = (u_c0.w + u_c1.y + uy.x + dy.x + u_zm1.x + u_zp1.x + g2_1.x) * SIXTH;
                wv11.y = (u_c1.x + u_c1.z + uy.y + dy.y + u_zm1.y + u_zp1.y + g2_1.y) * SIXTH;
                wv11.z = (u_c1.y + u_c1.w + uy.z + dy.z + u_zm1.z + u_zp1.z + g2_1.z) * SIXTH;
                wv11.w = (u_c1.z + cn.x   + uy.w + dy.w + u_zm1.w + u_zp1.w + g2_1.w) * SIXTH;
            }
        }
        if (act) { sw1[(t + 2) & 1][rp][pc0] = wv10; sw1[(t + 2) & 1][rp][pc1] = wv11; }
        w1_zm0 = w1_c0; w1_c0 = w1_zp0; w1_zp0 = wv10;
        w1_zm1 = w1_c1; w1_c1 = w1_zp1; w1_zp1 = wv11;

        // ---- W2: w2(t+1) from w1-ring + sw1[(t+1)&1] + g1 ----
        const int pw2 = t + 1;
        float4 wv20 = zero4(), wv21 = zero4();
        if (t >= z0 - 2 && pw2 >= 0 && pw2 < NI) {
            const int s = pw2 & 1;
            if (w2ok0) {
                const float4 uy = sw1[s][rp - 1][pc0];
                const float4 dy = sw1[s][rp + 1][pc0];
                const float4 cp = sw1[s][rp][pcm];
                wv20.x = (cp.w    + w1_c0.y + uy.x + dy.x + w1_zm0.x + w1_zp0.x + g1_0.x) * SIXTH;
                wv20.y = (w1_c0.x + w1_c0.z + uy.y + dy.y + w1_zm0.y + w1_zp0.y + g1_0.y) * SIXTH;
                wv20.z = (w1_c0.y + w1_c0.w + uy.z + dy.z + w1_zm0.z + w1_zp0.z + g1_0.z) * SIXTH;
                wv20.w = (w1_c0.z + w1_c1.x + uy.w + dy.w + w1_zm0.w + w1_zp0.w + g1_0.w) * SIXTH;
            }
            if (w2ok1) {
                const float4 uy = sw1[s][rp - 1][pc1];
                const float4 dy = sw1[s][rp + 1][pc1];
                const float4 cn = sw1[s][rp][pcp];
                wv21.x = (w1_c0.w + w1_c1.y + uy.x + dy.x + w1_zm1.x + w1_zp1.x + g1_1.x) * SIXTH;
                wv21.y = (w1_c1.x + w1_c1.z + uy.y + dy.y + w1_zm1.y + w1_zp1.y + g1_1.y) * SIXTH;
                wv21.z = (w1_c1.y + w1_c1.w + uy.z + dy.z + w1_zm1.z + w1_zp1.z + g1_1.z) * SIXTH;
                wv21.w = (w1_c1.z + cn.x    + uy.w + dy.w + w1_zm1.w + w1_zp1.w + g1_1.w) * SIXTH;
            }
        }
        if (act) { sw2[(t + 1) & 1][rp][pc0] = wv20; sw2[(t + 1) & 1][rp][pc1] = wv21; }
        w2_zm0 = w2_c0; w2_c0 = w2_zp0; w2_zp0 = wv20;
        w2_zm1 = w2_c1; w2_c1 = w2_zp1; w2_zp1 = wv21;

        // ---- O: out(t) from w2-ring + sw2[t&1] + g0 ----
        if (t >= z0) {
            const int s = t & 1;
            if (ook0) {
                const float4 uy = sw2[s][rp - 1][pc0];
                const float4 dy = sw2[s][rp + 1][pc0];
                const float4 cp = sw2[s][rp][pcm];       // perm(c0-1), c0>=1 guaranteed by ook0
                float4 ov;
                ov.x = (cp.w    + w2_c0.y + uy.x + dy.x + w2_zm0.x + w2_zp0.x + g0_0.x) * SIXTH;
                ov.y = (w2_c0.x + w2_c0.z + uy.y + dy.y + w2_zm0.y + w2_zp0.y + g0_0.y) * SIXTH;
                ov.z = (w2_c0.y + w2_c0.w + uy.z + dy.z + w2_zm0.z + w2_zp0.z + g0_0.z) * SIXTH;
                ov.w = (w2_c0.z + w2_c1.x + uy.w + dy.w + w2_zm0.w + w2_zp0.w + g0_0.w) * SIXTH;
                *reinterpret_cast<float4*>(&out[(size_t)t * plq + base0]) = ov;
            }
            if (ook1) {
                const float4 uy = sw2[s][rp - 1][pc1];
                const float4 dy = sw2[s][rp + 1][pc1];
                const float4 cn = sw2[s][rp][pcp];       // perm(c1+1), c1<=8 guaranteed by ook1
                float4 ov;
                ov.x = (w2_c0.w + w2_c1.y + uy.x + dy.x + w2_zm1.x + w2_zp1.x + g0_1.x) * SIXTH;
                ov.y = (w2_c1.x + w2_c1.z + uy.y + dy.y + w2_zm1.y + w2_zp1.y + g0_1.y) * SIXTH;
                ov.z = (w2_c1.y + w2_c1.w + uy.z + dy.z + w2_zm1.z + w2_zp1.z + g0_1.z) * SIXTH;
                ov.w = (w2_c1.z + cn.x    + uy.w + dy.w + w2_zm1.w + w2_zp1.w + g0_1.w) * SIXTH;
                *reinterpret_cast<float4*>(&out[(size_t)t * plq + base1]) = ov;
            }
        }
        __syncthreads();   // single barrier/iter (intra-iter slots disjoint)
    }
}

extern "C" void kernel_launch(void* const* d_in, const int* in_sizes, int n_in,
                              void* d_out, int out_size, void* d_ws, size_t ws_size,
                              hipStream_t stream) {
    const float* pre = (const float*)d_in[0];
    const float* f   = (const float*)d_in[1];
    float* out = (float*)d_out;
    float* buf = (float*)d_ws;
    const size_t nInt = (size_t)NI * NI * NI;
    float* g = buf + nInt;                           // g = h^2*f (ws >= 128 MiB)

    // 20 sweeps: step_first (1) + 6 fused triple (18) + 1 single.
    // first -> buf; P1 buf->out, ... P6 out->buf; last buf->out.
    step_first_v<<<dim3(1, NI / 4, NI), dim3(64, 4, 1), 0, stream>>>(pre, f, buf, g);

    float* cur = buf;
    float* nxt = out;
    dim3 fg(NI / TX, NI / TY, NI / CZ);              // 8x8x16 = 1024 blocks
    for (int i = 0; i < 6; ++i) {
        step_fused3x<<<fg, dim3(192, 1, 1), 0, stream>>>(cur, g, nxt);
        float* tmp = cur; cur = nxt; nxt = tmp;
    }
    // cur == buf after 6 swaps; final single sweep buf -> out.
    step_last_v<<<dim3(1, NI / 4, NI), dim3(64, 4, 1), 0, stream>>>(
        (const float4*)cur, (const float4*)g, (float4*)out);
}